// Round 7
// baseline (174.374 us; speedup 1.0000x reference)
//
#include <hip/hip_runtime.h>
#include <cstdint>
#include <cstddef>

// Problem constants
#define SS_ 256
#define LL_ 4
#define HH_ 1024

// ws layout (in floats)
#define ZM_OFF   ((size_t)0)                          // uint32 [2][64][8][8] = 8192 u32
#define PA_OFF   ((size_t)8192)                       // float [c8][t2][64][4][1024] = 4194304
#define DEN_OFF  ((size_t)(8192 + 4194304))           // float [c8][t2][64][4] = 4096

// ---------------------------------------------------------------------------
// Main fused kernel: layernorm + score + exp + online pooled accumulation.
// grid = 1024: idx = (t<<9) | (bb<<3) | c ; block = 512 (8 waves).
// Each block owns (t, b, s-chunk of 32) and ALL 4 layers; wave w handles
// layer l = w&3, s-parity soff = w>>2, 16 rows each. At step r the 8 waves
// read a contiguous 32 KB chunk; each block streams a contiguous 512 KB.
// vs round 6: grid 512 -> 1024 restores 4 blocks/CU = 32 waves/CU (round 6's
// 2 blocks/CU capped occupancy at 40% and delivered BW at ~3.3 TB/s; this is
// a latency-bound kernel, so resident-wave count is the BW lever).
// Hot loop is the proven 36-VGPR shape: single row buffer, p in regs, one
// merged 3-value 6-level shfl chain per row, mean-shift folded into cm.
// MODE 0: normal pass (assumes mask==1, records zero-row bitmasks).
// MODE 1: fixup; rebuilds first-zero index from bitmasks, early-exit if the
//         mask is all-ones for this (t,b) (true for this data).
// ---------------------------------------------------------------------------
template <int MODE>
__global__ __launch_bounds__(512) void attn_pool(const float* __restrict__ A_,
                                                 const float* __restrict__ B_,
                                                 const float* __restrict__ P_,
                                                 float* __restrict__ ws) {
  __shared__ float lds[8 * 1024];   // 32 KB combine buffer
  __shared__ float dshare[8];
  __shared__ int wmin[8];

  int idx = blockIdx.x;
  int c = idx & 7;
  int bb = (idx >> 3) & 63;
  int t = idx >> 9;
  int tid = threadIdx.x;
  int wid = tid >> 6;
  int ln = tid & 63;
  int l = wid & 3;      // this wave's layer
  int soff = wid >> 2;  // this wave's s parity (0/1)

  uint32_t* zmws = reinterpret_cast<uint32_t*>(ws);

  int fz = SS_;
  if (MODE == 1) {
    int myfz = SS_;
    if (tid < SS_) {
      int c_s = tid >> 5, sc = tid & 31;
      int par = sc & 1, r_s = sc >> 1;
      const uint32_t* zb = zmws + (((size_t)t * 64 + bb) * 8 + c_s) * 8 + par * 4;
      uint32_t all4 = ((zb[0] & zb[1] & zb[2] & zb[3]) >> r_s) & 1u;
      myfz = all4 ? tid : SS_;
    }
#pragma unroll
    for (int off = 32; off > 0; off >>= 1) myfz = min(myfz, __shfl_xor(myfz, off));
    if (ln == 0) wmin[wid] = myfz;
    __syncthreads();
#pragma unroll
    for (int w = 0; w < 8; ++w) fz = min(fz, wmin[w]);
    if (fz >= SS_) return;  // mask all-ones: keep pass-0 result
  }

  const float* __restrict__ X = t ? B_ : A_;

  // p[b,l,:] in registers (this wave's layer), same lane mapping as row loads
  float pv[16];
  {
    const float4* pr = reinterpret_cast<const float4*>(P_ + ((size_t)bb * LL_ + l) * HH_);
#pragma unroll
    for (int k = 0; k < 4; ++k) {
      float4 v = pr[k * 64 + ln];
      pv[4 * k + 0] = v.x; pv[4 * k + 1] = v.y;
      pv[4 * k + 2] = v.z; pv[4 * k + 3] = v.w;
    }
  }
  float sump = 0.f;
  {
#pragma unroll
    for (int j = 0; j < 16; ++j) sump += pv[j];
#pragma unroll
    for (int off = 32; off > 0; off >>= 1) sump += __shfl_xor(sump, off);
  }

  // block base: (b, s = c*32); wave base adds (soff*4 + l) rows of 1024
  const float* wbase = X + ((size_t)bb * SS_ + (size_t)c * 32) * (LL_ * HH_)
                         + (size_t)(soff * 4 + l) * HH_;

  float acc[16];
#pragma unroll
  for (int j = 0; j < 16; ++j) acc[j] = 0.f;
  float den = 0.f, cm = 0.f;
  uint32_t zm = 0;

  for (int r = 0; r < 16; ++r) {
    const float4* rp = reinterpret_cast<const float4*>(wbase + (size_t)r * (2 * LL_ * HH_));
    float x[16];
    {
      float4 v0 = rp[ln], v1 = rp[64 + ln], v2 = rp[128 + ln], v3 = rp[192 + ln];
      x[0] = v0.x;  x[1] = v0.y;  x[2] = v0.z;  x[3] = v0.w;
      x[4] = v1.x;  x[5] = v1.y;  x[6] = v1.z;  x[7] = v1.w;
      x[8] = v2.x;  x[9] = v2.y;  x[10] = v2.z; x[11] = v2.w;
      x[12] = v3.x; x[13] = v3.y; x[14] = v3.z; x[15] = v3.w;
    }
    float s1 = 0.f, s2 = 0.f, s3 = 0.f;
#pragma unroll
    for (int j = 0; j < 16; ++j) {
      s1 += x[j];
      s2 = fmaf(x[j], x[j], s2);
      s3 = fmaf(x[j], pv[j], s3);
    }
    // one merged 6-level chain for {s1,s2,s3}
#pragma unroll
    for (int off = 32; off > 0; off >>= 1) {
      s1 += __shfl_xor(s1, off);
      s2 += __shfl_xor(s2, off);
      s3 += __shfl_xor(s3, off);
    }
    float m_ = s1 * (1.f / 1024.f);
    float var_ = fmaf(-m_, m_, s2 * (1.f / 1024.f));
    float rstd_ = rsqrtf(var_ + 1e-5f);
    float d_ = (s3 - m_ * sump) * rstd_ * 0.03125f;
    float e_ = __expf(d_);
    if (MODE == 0) {
      zm |= (s2 == 0.f) ? (1u << r) : 0u;
    } else {
      int sg = c * 32 + 2 * r + soff;
      if (sg >= fz) e_ = 0.f;
    }
    float coef_ = e_ * rstd_;
#pragma unroll
    for (int j = 0; j < 16; ++j) acc[j] = fmaf(coef_, x[j], acc[j]);
    cm = fmaf(coef_, m_, cm);
    den += e_;
  }

  if (MODE == 0) {
    if (ln == 0)
      zmws[(((size_t)t * 64 + bb) * 8 + c) * 8 + wid] = zm;
  }

  // fold the mean-shift correction: pa_j = sum coef*x_j - sum coef*m
#pragma unroll
  for (int j = 0; j < 16; ++j) acc[j] -= cm;

  // combine: wave w and w+4 hold the two s-parity partials for layer l
#pragma unroll
  for (int k = 0; k < 4; ++k) {
#pragma unroll
    for (int j = 0; j < 4; ++j) lds[wid * 1024 + (k * 64 + ln) * 4 + j] = acc[4 * k + j];
  }
  if (ln == 0) dshare[wid] = den;
  __syncthreads();
  float* paq = ws + PA_OFF + (((size_t)c * 2 + t) * 64 + bb) * (4 * HH_);
  for (int e2 = tid; e2 < 4096; e2 += 512) {
    int lc = e2 >> 10, h = e2 & 1023;
    paq[(size_t)lc * HH_ + h] = lds[lc * 1024 + h] + lds[(lc + 4) * 1024 + h];
  }
  if (tid < 4) {
    ws[DEN_OFF + (((size_t)c * 2 + t) * 64 + bb) * 4 + tid] = dshare[tid] + dshare[tid + 4];
  }
}

// ---------------------------------------------------------------------------
// Merged head + out: per b, sum the 8 chunk-partials, normalize, compute
// y[b, l*16+o] for all l, then BN+ReLU, tanh encodings, final 66x3 matvec.
// grid = 64 (b), block = 256.
// ---------------------------------------------------------------------------
__global__ __launch_bounds__(256) void headout_kernel(
    const float* __restrict__ p, const float* __restrict__ fw, const float* __restrict__ fb,
    const float* __restrict__ ap, const float* __restrict__ bp,
    const float* __restrict__ gam, const float* __restrict__ bet,
    const float* __restrict__ rm, const float* __restrict__ rv,
    const float* __restrict__ msw, const float* __restrict__ msb,
    const float* __restrict__ dw, const float* __restrict__ db,
    const float* __restrict__ ws, float* __restrict__ out) {
  int bb = blockIdx.x;
  int t = threadIdx.x;
  __shared__ float red[256 * 17 + 16 * 17];
  __shared__ float yv[64];
  const float* den = ws + DEN_OFF;

  for (int l = 0; l < 4; ++l) {
    float sden_a = 1e-15f, sden_b = 1e-15f;
#pragma unroll
    for (int qq = 0; qq < 8; ++qq) {
      sden_a += den[(((size_t)qq * 2 + 0) * 64 + bb) * 4 + l];
      sden_b += den[(((size_t)qq * 2 + 1) * 64 + bb) * 4 + l];
    }
    float inv_a = 1.0f / sden_a;
    float inv_b = 1.0f / sden_b;

    float4 A = make_float4(0.f, 0.f, 0.f, 0.f), B = make_float4(0.f, 0.f, 0.f, 0.f);
#pragma unroll
    for (int qq = 0; qq < 8; ++qq) {
      const float4* pa_ = reinterpret_cast<const float4*>(
          ws + PA_OFF + ((((size_t)qq * 2 + 0) * 64 + bb) * 4 + l) * HH_);
      const float4* pb_ = reinterpret_cast<const float4*>(
          ws + PA_OFF + ((((size_t)qq * 2 + 1) * 64 + bb) * 4 + l) * HH_);
      float4 va = pa_[t], vb = pb_[t];
      A.x += va.x; A.y += va.y; A.z += va.z; A.w += va.w;
      B.x += vb.x; B.y += vb.y; B.z += vb.z; B.w += vb.w;
    }

    float4 pv = reinterpret_cast<const float4*>(p + ((size_t)bb * LL_ + l) * HH_)[t];
    float av[4] = {A.x * inv_a, A.y * inv_a, A.z * inv_a, A.w * inv_a};
    float bv[4] = {B.x * inv_b, B.y * inv_b, B.z * inv_b, B.w * inv_b};
    float cp[4] = {pv.x, pv.y, pv.z, pv.w};

    float part[16];
#pragma unroll
    for (int o = 0; o < 16; ++o) part[o] = 0.f;

    const float* wl = fw + (size_t)l * 5120 * 16;
#pragma unroll
    for (int j = 0; j < 4; ++j) {
      int h = t * 4 + j;
      float c[5] = {cp[j], av[j], bv[j], cp[j] * av[j], cp[j] * bv[j]};
#pragma unroll
      for (int sec = 0; sec < 5; ++sec) {
        const float4* wr = reinterpret_cast<const float4*>(wl + ((size_t)sec * 1024 + h) * 16);
#pragma unroll
        for (int o4 = 0; o4 < 4; ++o4) {
          float4 w4 = wr[o4];
          part[o4 * 4 + 0] += c[sec] * w4.x;
          part[o4 * 4 + 1] += c[sec] * w4.y;
          part[o4 * 4 + 2] += c[sec] * w4.z;
          part[o4 * 4 + 3] += c[sec] * w4.w;
        }
      }
    }

#pragma unroll
    for (int o = 0; o < 16; ++o) red[t * 17 + o] = part[o];
    __syncthreads();
    {
      int o = t & 15, g = t >> 4;
      float sacc = 0.f;
#pragma unroll
      for (int i = 0; i < 16; ++i) sacc += red[(g * 16 + i) * 17 + o];
      red[256 * 17 + g * 17 + o] = sacc;
    }
    __syncthreads();
    if (t < 16) {
      float sacc = 0.f;
#pragma unroll
      for (int g = 0; g < 16; ++g) sacc += red[256 * 17 + g * 17 + t];
      yv[l * 16 + t] = sacc + fb[l * 16 + t];
    }
    __syncthreads();
  }

  if (t < 64) {
    int k = t;
    float y = yv[k];
    y = (y - rm[k]) * rsqrtf(rv[k] + 1e-5f) * gam[k] + bet[k];
    y = fmaxf(y, 0.f);
    float w0 = dw[0], b0 = db[0];
    float ape = tanhf(ap[bb] * w0 + b0);
    float bpe = tanhf(bp[bb] * w0 + b0);
#pragma unroll
    for (int c = 0; c < 3; ++c) {
      float v = y * msw[k * 3 + c];
#pragma unroll
      for (int off = 32; off > 0; off >>= 1) v += __shfl_xor(v, off);
      if (k == 0) out[bb * 3 + c] = v + ape * msw[64 * 3 + c] + bpe * msw[65 * 3 + c] + msb[c];
    }
  }
}

extern "C" void kernel_launch(void* const* d_in, const int* in_sizes, int n_in,
                              void* d_out, int out_size, void* d_ws, size_t ws_size,
                              hipStream_t stream) {
  (void)in_sizes; (void)n_in; (void)out_size; (void)ws_size;
  const float* a = (const float*)d_in[0];
  const float* b = (const float*)d_in[1];
  const float* p = (const float*)d_in[2];
  const float* ap = (const float*)d_in[3];
  const float* bp = (const float*)d_in[4];
  const float* ffnn_w = (const float*)d_in[5];
  const float* ffnn_b = (const float*)d_in[6];
  const float* bn_g = (const float*)d_in[7];
  const float* bn_b = (const float*)d_in[8];
  const float* bn_rm = (const float*)d_in[9];
  const float* bn_rv = (const float*)d_in[10];
  const float* ms_w = (const float*)d_in[11];
  const float* ms_b = (const float*)d_in[12];
  const float* dist_w = (const float*)d_in[13];
  const float* dist_b = (const float*)d_in[14];
  float* ws = (float*)d_ws;
  float* out = (float*)d_out;

  hipLaunchKernelGGL((attn_pool<0>), dim3(1024), dim3(512), 0, stream, a, b, p, ws);
  hipLaunchKernelGGL((attn_pool<1>), dim3(1024), dim3(512), 0, stream, a, b, p, ws);
  hipLaunchKernelGGL(headout_kernel, dim3(64), dim3(256), 0, stream,
                     p, ffnn_w, ffnn_b, ap, bp, bn_g, bn_b, bn_rm, bn_rv,
                     ms_w, ms_b, dist_w, dist_b, ws, out);
}

// Round 8
// 157.136 us; speedup vs baseline: 1.1097x; 1.1097x over previous
//
#include <hip/hip_runtime.h>
#include <cstdint>
#include <cstddef>

// Problem constants
#define SS_ 256
#define LL_ 4
#define HH_ 1024

// ws layout (in floats)
#define ZM_OFF   ((size_t)0)                          // uint32 [2][64][4][8] = 4096 u32
#define PA_OFF   ((size_t)4096)                       // float [q4][t2][64][4][1024] = 2097152
#define DEN_OFF  ((size_t)(4096 + 2097152))           // float [q4][t2][64][4] = 2048

// ---------------------------------------------------------------------------
// Main fused kernel: layernorm + score + exp + online pooled accumulation.
// grid = 512: idx = (t<<8) | (bb<<2) | q ; block = 512 (8 waves).
// Each block owns (t, b, s-quarter of 64) and ALL 4 layers; wave w handles
// layer l = w&3, s-parity soff = w>>2, 32 rows each.
// THIS ROUND: 2-row ILP. Each iteration loads TWO rows (8 x dwordx4 = 8 KB
// in flight per wave-visit) and runs ONE 6-level shfl chain reducing all six
// sums {s1,s2,s3} x {u,v}. Rationale: all prior layouts pinned at ~3.3 TB/s
// delivered with waves ~always in vmcnt-wait; the cap is per-wave issue
// serialization (4 KB issued, then ~400 cyc silent). Doubling bytes/visit
// and halving chain cost per row directly raises aggregate issue rate.
// Flat code, no lambdas/asm/DMA; __launch_bounds__(512,1) frees the
// allocator (live set ~100 VGPR) -- spill check = WRITE_SIZE.
// MODE 0: normal pass (assumes mask==1, records zero-row bitmasks).
// MODE 1: fixup; rebuilds first-zero index from bitmasks, early-exit if the
//         mask is all-ones for this (t,b) (true for this data).
// ---------------------------------------------------------------------------
template <int MODE>
__global__ __launch_bounds__(512, 1) void attn_pool(const float* __restrict__ A_,
                                                    const float* __restrict__ B_,
                                                    const float* __restrict__ P_,
                                                    float* __restrict__ ws) {
  __shared__ float lds[8 * 1024];   // 32 KB combine buffer
  __shared__ float dshare[8];
  __shared__ int wmin[8];

  int idx = blockIdx.x;
  int q = idx & 3;
  int bb = (idx >> 2) & 63;
  int t = idx >> 8;
  int tid = threadIdx.x;
  int wid = tid >> 6;
  int ln = tid & 63;
  int l = wid & 3;      // this wave's layer
  int soff = wid >> 2;  // this wave's s parity (0/1)

  uint32_t* zmws = reinterpret_cast<uint32_t*>(ws);

  int fz = SS_;
  if (MODE == 1) {
    int myfz = SS_;
    if (tid < SS_) {
      int q_s = tid >> 6, sl_s = tid & 63;
      int w_s = (sl_s & 1) * 4, r_s = sl_s >> 1;
      const uint32_t* zb = zmws + (((size_t)t * 64 + bb) * 4 + q_s) * 8 + w_s;
      uint32_t all4 = ((zb[0] & zb[1] & zb[2] & zb[3]) >> r_s) & 1u;
      myfz = all4 ? tid : SS_;
    }
#pragma unroll
    for (int off = 32; off > 0; off >>= 1) myfz = min(myfz, __shfl_xor(myfz, off));
    if (ln == 0) wmin[wid] = myfz;
    __syncthreads();
#pragma unroll
    for (int w = 0; w < 8; ++w) fz = min(fz, wmin[w]);
    if (fz >= SS_) return;  // mask all-ones: keep pass-0 result
  }

  const float* __restrict__ X = t ? B_ : A_;

  // p[b,l,:] in registers (this wave's layer), same lane mapping as row loads
  float pv[16];
  {
    const float4* pr = reinterpret_cast<const float4*>(P_ + ((size_t)bb * LL_ + l) * HH_);
#pragma unroll
    for (int k = 0; k < 4; ++k) {
      float4 v = pr[k * 64 + ln];
      pv[4 * k + 0] = v.x; pv[4 * k + 1] = v.y;
      pv[4 * k + 2] = v.z; pv[4 * k + 3] = v.w;
    }
  }
  float sump = 0.f;
  {
#pragma unroll
    for (int j = 0; j < 16; ++j) sump += pv[j];
#pragma unroll
    for (int off = 32; off > 0; off >>= 1) sump += __shfl_xor(sump, off);
  }

  // block base: (b, s = q*64); wave base adds (soff*4 + l) rows of 1024
  const float* wbase = X + ((size_t)bb * SS_ + (size_t)q * 64) * (LL_ * HH_)
                         + (size_t)(soff * 4 + l) * HH_;

  float acc[16];
#pragma unroll
  for (int j = 0; j < 16; ++j) acc[j] = 0.f;
  float den = 0.f, cm = 0.f;
  uint32_t zm = 0;

  for (int i = 0; i < 16; ++i) {
    // two rows: r = 2i and 2i+1 (wave-row stride is 2*LL*HH floats = 8192)
    const float4* rpA = reinterpret_cast<const float4*>(wbase + (size_t)(2 * i) * 8192);
    const float4* rpB = reinterpret_cast<const float4*>(wbase + (size_t)(2 * i + 1) * 8192);
    float u[16], v[16];
    {
      float4 a0 = rpA[ln], a1 = rpA[64 + ln], a2 = rpA[128 + ln], a3 = rpA[192 + ln];
      float4 b0 = rpB[ln], b1 = rpB[64 + ln], b2 = rpB[128 + ln], b3 = rpB[192 + ln];
      u[0] = a0.x;  u[1] = a0.y;  u[2] = a0.z;  u[3] = a0.w;
      u[4] = a1.x;  u[5] = a1.y;  u[6] = a1.z;  u[7] = a1.w;
      u[8] = a2.x;  u[9] = a2.y;  u[10] = a2.z; u[11] = a2.w;
      u[12] = a3.x; u[13] = a3.y; u[14] = a3.z; u[15] = a3.w;
      v[0] = b0.x;  v[1] = b0.y;  v[2] = b0.z;  v[3] = b0.w;
      v[4] = b1.x;  v[5] = b1.y;  v[6] = b1.z;  v[7] = b1.w;
      v[8] = b2.x;  v[9] = b2.y;  v[10] = b2.z; v[11] = b2.w;
      v[12] = b3.x; v[13] = b3.y; v[14] = b3.z; v[15] = b3.w;
    }
    float s1a = 0.f, s2a = 0.f, s3a = 0.f;
    float s1b = 0.f, s2b = 0.f, s3b = 0.f;
#pragma unroll
    for (int j = 0; j < 16; ++j) {
      s1a += u[j];
      s2a = fmaf(u[j], u[j], s2a);
      s3a = fmaf(u[j], pv[j], s3a);
      s1b += v[j];
      s2b = fmaf(v[j], v[j], s2b);
      s3b = fmaf(v[j], pv[j], s3b);
    }
    // ONE merged 6-level chain for all six sums
#pragma unroll
    for (int off = 32; off > 0; off >>= 1) {
      s1a += __shfl_xor(s1a, off);
      s2a += __shfl_xor(s2a, off);
      s3a += __shfl_xor(s3a, off);
      s1b += __shfl_xor(s1b, off);
      s2b += __shfl_xor(s2b, off);
      s3b += __shfl_xor(s3b, off);
    }
    // row u epilogue
    {
      float m_ = s1a * (1.f / 1024.f);
      float var_ = fmaf(-m_, m_, s2a * (1.f / 1024.f));
      float rstd_ = rsqrtf(var_ + 1e-5f);
      float d_ = (s3a - m_ * sump) * rstd_ * 0.03125f;
      float e_ = __expf(d_);
      if (MODE == 0) {
        zm |= (s2a == 0.f) ? (1u << (2 * i)) : 0u;
      } else {
        int sg = q * 64 + 4 * i + soff;
        if (sg >= fz) e_ = 0.f;
      }
      float coef_ = e_ * rstd_;
#pragma unroll
      for (int j = 0; j < 16; ++j) acc[j] = fmaf(coef_, u[j], acc[j]);
      cm = fmaf(coef_, m_, cm);
      den += e_;
    }
    // row v epilogue
    {
      float m_ = s1b * (1.f / 1024.f);
      float var_ = fmaf(-m_, m_, s2b * (1.f / 1024.f));
      float rstd_ = rsqrtf(var_ + 1e-5f);
      float d_ = (s3b - m_ * sump) * rstd_ * 0.03125f;
      float e_ = __expf(d_);
      if (MODE == 0) {
        zm |= (s2b == 0.f) ? (1u << (2 * i + 1)) : 0u;
      } else {
        int sg = q * 64 + 4 * i + 2 + soff;
        if (sg >= fz) e_ = 0.f;
      }
      float coef_ = e_ * rstd_;
#pragma unroll
      for (int j = 0; j < 16; ++j) acc[j] = fmaf(coef_, v[j], acc[j]);
      cm = fmaf(coef_, m_, cm);
      den += e_;
    }
  }

  if (MODE == 0) {
    if (ln == 0)
      zmws[(((size_t)t * 64 + bb) * 4 + q) * 8 + wid] = zm;
  }

  // fold the mean-shift correction: pa_j = sum coef*x_j - sum coef*m
#pragma unroll
  for (int j = 0; j < 16; ++j) acc[j] -= cm;

  // combine: wave w and w+4 hold the two s-parity partials for layer l
#pragma unroll
  for (int k = 0; k < 4; ++k) {
#pragma unroll
    for (int j = 0; j < 4; ++j) lds[wid * 1024 + (k * 64 + ln) * 4 + j] = acc[4 * k + j];
  }
  if (ln == 0) dshare[wid] = den;
  __syncthreads();
  float* paq = ws + PA_OFF + (((size_t)q * 2 + t) * 64 + bb) * (4 * HH_);
  for (int e2 = tid; e2 < 4096; e2 += 512) {
    int lc = e2 >> 10, h = e2 & 1023;
    paq[(size_t)lc * HH_ + h] = lds[lc * 1024 + h] + lds[(lc + 4) * 1024 + h];
  }
  if (tid < 4) {
    ws[DEN_OFF + (((size_t)q * 2 + t) * 64 + bb) * 4 + tid] = dshare[tid] + dshare[tid + 4];
  }
}

// ---------------------------------------------------------------------------
// Merged head + out: per b, sum the 4 quarter-partials, normalize, compute
// y[b, l*16+o] for all l, then BN+ReLU, tanh encodings, final 66x3 matvec.
// grid = 64 (b), block = 256.
// ---------------------------------------------------------------------------
__global__ __launch_bounds__(256) void headout_kernel(
    const float* __restrict__ p, const float* __restrict__ fw, const float* __restrict__ fb,
    const float* __restrict__ ap, const float* __restrict__ bp,
    const float* __restrict__ gam, const float* __restrict__ bet,
    const float* __restrict__ rm, const float* __restrict__ rv,
    const float* __restrict__ msw, const float* __restrict__ msb,
    const float* __restrict__ dw, const float* __restrict__ db,
    const float* __restrict__ ws, float* __restrict__ out) {
  int bb = blockIdx.x;
  int t = threadIdx.x;
  __shared__ float red[256 * 17 + 16 * 17];
  __shared__ float yv[64];
  const float* den = ws + DEN_OFF;

  for (int l = 0; l < 4; ++l) {
    float sden_a = 1e-15f, sden_b = 1e-15f;
#pragma unroll
    for (int qq = 0; qq < 4; ++qq) {
      sden_a += den[(((size_t)qq * 2 + 0) * 64 + bb) * 4 + l];
      sden_b += den[(((size_t)qq * 2 + 1) * 64 + bb) * 4 + l];
    }
    float inv_a = 1.0f / sden_a;
    float inv_b = 1.0f / sden_b;

    float4 A = make_float4(0.f, 0.f, 0.f, 0.f), B = make_float4(0.f, 0.f, 0.f, 0.f);
#pragma unroll
    for (int qq = 0; qq < 4; ++qq) {
      const float4* pa_ = reinterpret_cast<const float4*>(
          ws + PA_OFF + ((((size_t)qq * 2 + 0) * 64 + bb) * 4 + l) * HH_);
      const float4* pb_ = reinterpret_cast<const float4*>(
          ws + PA_OFF + ((((size_t)qq * 2 + 1) * 64 + bb) * 4 + l) * HH_);
      float4 va = pa_[t], vb = pb_[t];
      A.x += va.x; A.y += va.y; A.z += va.z; A.w += va.w;
      B.x += vb.x; B.y += vb.y; B.z += vb.z; B.w += vb.w;
    }

    float4 pv = reinterpret_cast<const float4*>(p + ((size_t)bb * LL_ + l) * HH_)[t];
    float av[4] = {A.x * inv_a, A.y * inv_a, A.z * inv_a, A.w * inv_a};
    float bv[4] = {B.x * inv_b, B.y * inv_b, B.z * inv_b, B.w * inv_b};
    float cp[4] = {pv.x, pv.y, pv.z, pv.w};

    float part[16];
#pragma unroll
    for (int o = 0; o < 16; ++o) part[o] = 0.f;

    const float* wl = fw + (size_t)l * 5120 * 16;
#pragma unroll
    for (int j = 0; j < 4; ++j) {
      int h = t * 4 + j;
      float c[5] = {cp[j], av[j], bv[j], cp[j] * av[j], cp[j] * bv[j]};
#pragma unroll
      for (int sec = 0; sec < 5; ++sec) {
        const float4* wr = reinterpret_cast<const float4*>(wl + ((size_t)sec * 1024 + h) * 16);
#pragma unroll
        for (int o4 = 0; o4 < 4; ++o4) {
          float4 w4 = wr[o4];
          part[o4 * 4 + 0] += c[sec] * w4.x;
          part[o4 * 4 + 1] += c[sec] * w4.y;
          part[o4 * 4 + 2] += c[sec] * w4.z;
          part[o4 * 4 + 3] += c[sec] * w4.w;
        }
      }
    }

#pragma unroll
    for (int o = 0; o < 16; ++o) red[t * 17 + o] = part[o];
    __syncthreads();
    {
      int o = t & 15, g = t >> 4;
      float sacc = 0.f;
#pragma unroll
      for (int i = 0; i < 16; ++i) sacc += red[(g * 16 + i) * 17 + o];
      red[256 * 17 + g * 17 + o] = sacc;
    }
    __syncthreads();
    if (t < 16) {
      float sacc = 0.f;
#pragma unroll
      for (int g = 0; g < 16; ++g) sacc += red[256 * 17 + g * 17 + t];
      yv[l * 16 + t] = sacc + fb[l * 16 + t];
    }
    __syncthreads();
  }

  if (t < 64) {
    int k = t;
    float y = yv[k];
    y = (y - rm[k]) * rsqrtf(rv[k] + 1e-5f) * gam[k] + bet[k];
    y = fmaxf(y, 0.f);
    float w0 = dw[0], b0 = db[0];
    float ape = tanhf(ap[bb] * w0 + b0);
    float bpe = tanhf(bp[bb] * w0 + b0);
#pragma unroll
    for (int c = 0; c < 3; ++c) {
      float v = y * msw[k * 3 + c];
#pragma unroll
      for (int off = 32; off > 0; off >>= 1) v += __shfl_xor(v, off);
      if (k == 0) out[bb * 3 + c] = v + ape * msw[64 * 3 + c] + bpe * msw[65 * 3 + c] + msb[c];
    }
  }
}

extern "C" void kernel_launch(void* const* d_in, const int* in_sizes, int n_in,
                              void* d_out, int out_size, void* d_ws, size_t ws_size,
                              hipStream_t stream) {
  (void)in_sizes; (void)n_in; (void)out_size; (void)ws_size;
  const float* a = (const float*)d_in[0];
  const float* b = (const float*)d_in[1];
  const float* p = (const float*)d_in[2];
  const float* ap = (const float*)d_in[3];
  const float* bp = (const float*)d_in[4];
  const float* ffnn_w = (const float*)d_in[5];
  const float* ffnn_b = (const float*)d_in[6];
  const float* bn_g = (const float*)d_in[7];
  const float* bn_b = (const float*)d_in[8];
  const float* bn_rm = (const float*)d_in[9];
  const float* bn_rv = (const float*)d_in[10];
  const float* ms_w = (const float*)d_in[11];
  const float* ms_b = (const float*)d_in[12];
  const float* dist_w = (const float*)d_in[13];
  const float* dist_b = (const float*)d_in[14];
  float* ws = (float*)d_ws;
  float* out = (float*)d_out;

  hipLaunchKernelGGL((attn_pool<0>), dim3(512), dim3(512), 0, stream, a, b, p, ws);
  hipLaunchKernelGGL((attn_pool<1>), dim3(512), dim3(512), 0, stream, a, b, p, ws);
  hipLaunchKernelGGL(headout_kernel, dim3(64), dim3(256), 0, stream,
                     p, ffnn_w, ffnn_b, ap, bp, bn_g, bn_b, bn_rm, bn_rv,
                     ms_w, ms_b, dist_w, dist_b, ws, out);
}

// Round 9
// 156.047 us; speedup vs baseline: 1.1174x; 1.0070x over previous
//
#include <hip/hip_runtime.h>
#include <cstdint>
#include <cstddef>

// Problem constants
#define SS_ 256
#define LL_ 4
#define HH_ 1024

// ws layout (in floats)
#define ZM_OFF   ((size_t)0)                          // uint32 [2][64][4][8] = 4096 u32
#define PA_OFF   ((size_t)4096)                       // float [q4][t2][64][4][1024] = 2097152
#define DEN_OFF  ((size_t)(4096 + 2097152))           // float [q4][t2][64][4] = 2048

// ---------------------------------------------------------------------------
// Main fused kernel: layernorm + score + exp + online pooled accumulation.
// grid = 512: idx = (t<<8) | (bb<<2) | q ; block = 512 (8 waves).
// Wave w: layer l = w&3, s-parity soff = w>>2, 32 rows (16 pairs).
// THIS ROUND: true software pipeline at pair granularity. Two named register
// sets of 8 float4 (A/B); pair i+1's 8 loads (8 KB) are issued BEFORE pair i
// is processed, and the float4 values are consumed directly (no scalar-array
// repack), so the live set (~116 VGPR) forces the allocator to keep the burst
// in flight across the whole ~600-cycle reduce phase. launch_bounds(512,1)
// gives the allocator budget (r8's 48-VGPR allocation proved the compiler
// serialized the loads otherwise). Spill check = WRITE_SIZE (~8 MB clean).
// MODE 0: normal pass (assumes mask==1, records zero-row bitmasks).
// MODE 1: fixup; rebuilds first-zero index, early-exit if mask all-ones.
// ---------------------------------------------------------------------------

#define LD8(S, i)                                                              \
  {                                                                            \
    const float4* ra_ = rp0 + (size_t)(2 * (i)) * 2048;                        \
    const float4* rb_ = ra_ + 2048;                                            \
    S##0 = ra_[ln]; S##1 = ra_[64 + ln]; S##2 = ra_[128 + ln]; S##3 = ra_[192 + ln]; \
    S##4 = rb_[ln]; S##5 = rb_[64 + ln]; S##6 = rb_[128 + ln]; S##7 = rb_[192 + ln]; \
  }

#define ROWSUMS(r0, r1, r2, r3, s1, s2, s3)                                    \
  {                                                                            \
    s1 = (((r0.x + r0.y) + (r0.z + r0.w)) + ((r1.x + r1.y) + (r1.z + r1.w))) + \
         (((r2.x + r2.y) + (r2.z + r2.w)) + ((r3.x + r3.y) + (r3.z + r3.w)));  \
    s2 = fmaf(r0.x, r0.x, fmaf(r0.y, r0.y, fmaf(r0.z, r0.z, fmaf(r0.w, r0.w,   \
         fmaf(r1.x, r1.x, fmaf(r1.y, r1.y, fmaf(r1.z, r1.z, fmaf(r1.w, r1.w,   \
         fmaf(r2.x, r2.x, fmaf(r2.y, r2.y, fmaf(r2.z, r2.z, fmaf(r2.w, r2.w,   \
         fmaf(r3.x, r3.x, fmaf(r3.y, r3.y, fmaf(r3.z, r3.z, fmaf(r3.w, r3.w,   \
         0.f))))))))))))))));                                                  \
    s3 = fmaf(r0.x, pv0.x, fmaf(r0.y, pv0.y, fmaf(r0.z, pv0.z, fmaf(r0.w, pv0.w, \
         fmaf(r1.x, pv1.x, fmaf(r1.y, pv1.y, fmaf(r1.z, pv1.z, fmaf(r1.w, pv1.w, \
         fmaf(r2.x, pv2.x, fmaf(r2.y, pv2.y, fmaf(r2.z, pv2.z, fmaf(r2.w, pv2.w, \
         fmaf(r3.x, pv3.x, fmaf(r3.y, pv3.y, fmaf(r3.z, pv3.z, fmaf(r3.w, pv3.w, \
         0.f))))))))))))))));                                                  \
  }

#define EPI(r0, r1, r2, r3, s1, s2, s3, bit, sg)                               \
  {                                                                            \
    float m_ = s1 * (1.f / 1024.f);                                            \
    float var_ = fmaf(-m_, m_, s2 * (1.f / 1024.f));                           \
    float rstd_ = rsqrtf(var_ + 1e-5f);                                        \
    float d_ = (s3 - m_ * sump) * rstd_ * 0.03125f;                            \
    float e_ = __expf(d_);                                                     \
    if (MODE == 0) {                                                           \
      zm |= (s2 == 0.f) ? (1u << (bit)) : 0u;                                  \
    } else {                                                                   \
      if ((sg) >= fz) e_ = 0.f;                                                \
    }                                                                          \
    float coef_ = e_ * rstd_;                                                  \
    acc0.x = fmaf(coef_, r0.x, acc0.x); acc0.y = fmaf(coef_, r0.y, acc0.y);    \
    acc0.z = fmaf(coef_, r0.z, acc0.z); acc0.w = fmaf(coef_, r0.w, acc0.w);    \
    acc1.x = fmaf(coef_, r1.x, acc1.x); acc1.y = fmaf(coef_, r1.y, acc1.y);    \
    acc1.z = fmaf(coef_, r1.z, acc1.z); acc1.w = fmaf(coef_, r1.w, acc1.w);    \
    acc2.x = fmaf(coef_, r2.x, acc2.x); acc2.y = fmaf(coef_, r2.y, acc2.y);    \
    acc2.z = fmaf(coef_, r2.z, acc2.z); acc2.w = fmaf(coef_, r2.w, acc2.w);    \
    acc3.x = fmaf(coef_, r3.x, acc3.x); acc3.y = fmaf(coef_, r3.y, acc3.y);    \
    acc3.z = fmaf(coef_, r3.z, acc3.z); acc3.w = fmaf(coef_, r3.w, acc3.w);    \
    cm = fmaf(coef_, m_, cm);                                                  \
    den += e_;                                                                 \
  }

#define PROC8(S, i)                                                            \
  {                                                                            \
    float s1a, s2a, s3a, s1b, s2b, s3b;                                        \
    ROWSUMS(S##0, S##1, S##2, S##3, s1a, s2a, s3a);                            \
    ROWSUMS(S##4, S##5, S##6, S##7, s1b, s2b, s3b);                            \
    _Pragma("unroll")                                                          \
    for (int off_ = 32; off_ > 0; off_ >>= 1) {                                \
      s1a += __shfl_xor(s1a, off_);                                            \
      s2a += __shfl_xor(s2a, off_);                                            \
      s3a += __shfl_xor(s3a, off_);                                            \
      s1b += __shfl_xor(s1b, off_);                                            \
      s2b += __shfl_xor(s2b, off_);                                            \
      s3b += __shfl_xor(s3b, off_);                                            \
    }                                                                          \
    EPI(S##0, S##1, S##2, S##3, s1a, s2a, s3a, 2 * (i), q * 64 + 4 * (i) + soff); \
    EPI(S##4, S##5, S##6, S##7, s1b, s2b, s3b, 2 * (i) + 1, q * 64 + 4 * (i) + 2 + soff); \
  }

template <int MODE>
__global__ __launch_bounds__(512, 1) void attn_pool(const float* __restrict__ A_,
                                                    const float* __restrict__ B_,
                                                    const float* __restrict__ P_,
                                                    float* __restrict__ ws) {
  __shared__ float lds[8 * 1024];   // 32 KB combine buffer
  __shared__ float dshare[8];
  __shared__ int wmin[8];

  int idx = blockIdx.x;
  int q = idx & 3;
  int bb = (idx >> 2) & 63;
  int t = idx >> 8;
  int tid = threadIdx.x;
  int wid = tid >> 6;
  int ln = tid & 63;
  int l = wid & 3;      // this wave's layer
  int soff = wid >> 2;  // this wave's s parity (0/1)

  uint32_t* zmws = reinterpret_cast<uint32_t*>(ws);

  int fz = SS_;
  if (MODE == 1) {
    int myfz = SS_;
    if (tid < SS_) {
      int q_s = tid >> 6, sl_s = tid & 63;
      int w_s = (sl_s & 1) * 4, r_s = sl_s >> 1;
      const uint32_t* zb = zmws + (((size_t)t * 64 + bb) * 4 + q_s) * 8 + w_s;
      uint32_t all4 = ((zb[0] & zb[1] & zb[2] & zb[3]) >> r_s) & 1u;
      myfz = all4 ? tid : SS_;
    }
#pragma unroll
    for (int off = 32; off > 0; off >>= 1) myfz = min(myfz, __shfl_xor(myfz, off));
    if (ln == 0) wmin[wid] = myfz;
    __syncthreads();
#pragma unroll
    for (int w = 0; w < 8; ++w) fz = min(fz, wmin[w]);
    if (fz >= SS_) return;  // mask all-ones: keep pass-0 result
  }

  const float* __restrict__ X = t ? B_ : A_;

  // p[b,l,:] in registers (this wave's layer), same lane mapping as row loads
  float4 pv0, pv1, pv2, pv3;
  {
    const float4* pr = reinterpret_cast<const float4*>(P_ + ((size_t)bb * LL_ + l) * HH_);
    pv0 = pr[ln]; pv1 = pr[64 + ln]; pv2 = pr[128 + ln]; pv3 = pr[192 + ln];
  }
  float sump;
  {
    sump = ((pv0.x + pv0.y) + (pv0.z + pv0.w)) + ((pv1.x + pv1.y) + (pv1.z + pv1.w)) +
           ((pv2.x + pv2.y) + (pv2.z + pv2.w)) + ((pv3.x + pv3.y) + (pv3.z + pv3.w));
#pragma unroll
    for (int off = 32; off > 0; off >>= 1) sump += __shfl_xor(sump, off);
  }

  // block base: (b, s = q*64); wave base adds (soff*4 + l) rows of 1024
  const float* wbase = X + ((size_t)bb * SS_ + (size_t)q * 64) * (LL_ * HH_)
                         + (size_t)(soff * 4 + l) * HH_;
  const float4* rp0 = reinterpret_cast<const float4*>(wbase);  // pair i at rp0 + 2i*2048

  float4 acc0, acc1, acc2, acc3;
  acc0 = acc1 = acc2 = acc3 = make_float4(0.f, 0.f, 0.f, 0.f);
  float den = 0.f, cm = 0.f;
  uint32_t zm = 0;

  float4 A0, A1, A2, A3, A4, A5, A6, A7;
  float4 B0, B1, B2, B3, B4, B5, B6, B7;

  // software pipeline over 16 pairs: pair i+1's loads issue before PROC(pair i)
  LD8(A, 0);
  for (int i = 0; i < 15; i += 2) {
    LD8(B, i + 1);
    PROC8(A, i);
    if (i + 2 < 16) LD8(A, i + 2);
    PROC8(B, i + 1);
  }

  if (MODE == 0) {
    if (ln == 0)
      zmws[(((size_t)t * 64 + bb) * 4 + q) * 8 + wid] = zm;
  }

  // fold the mean-shift correction: pa_j = sum coef*x_j - sum coef*m
  acc0.x -= cm; acc0.y -= cm; acc0.z -= cm; acc0.w -= cm;
  acc1.x -= cm; acc1.y -= cm; acc1.z -= cm; acc1.w -= cm;
  acc2.x -= cm; acc2.y -= cm; acc2.z -= cm; acc2.w -= cm;
  acc3.x -= cm; acc3.y -= cm; acc3.z -= cm; acc3.w -= cm;

  // combine: wave w and w+4 hold the two s-parity partials for layer l
  *reinterpret_cast<float4*>(&lds[wid * 1024 + (0 * 64 + ln) * 4]) = acc0;
  *reinterpret_cast<float4*>(&lds[wid * 1024 + (1 * 64 + ln) * 4]) = acc1;
  *reinterpret_cast<float4*>(&lds[wid * 1024 + (2 * 64 + ln) * 4]) = acc2;
  *reinterpret_cast<float4*>(&lds[wid * 1024 + (3 * 64 + ln) * 4]) = acc3;
  if (ln == 0) dshare[wid] = den;
  __syncthreads();
  float* paq = ws + PA_OFF + (((size_t)q * 2 + t) * 64 + bb) * (4 * HH_);
  for (int e2 = tid; e2 < 4096; e2 += 512) {
    int lc = e2 >> 10, h = e2 & 1023;
    paq[(size_t)lc * HH_ + h] = lds[lc * 1024 + h] + lds[(lc + 4) * 1024 + h];
  }
  if (tid < 4) {
    ws[DEN_OFF + (((size_t)q * 2 + t) * 64 + bb) * 4 + tid] = dshare[tid] + dshare[tid + 4];
  }
}

// ---------------------------------------------------------------------------
// Merged head + out: per b, sum the 4 quarter-partials, normalize, compute
// y[b, l*16+o] for all l, then BN+ReLU, tanh encodings, final 66x3 matvec.
// grid = 64 (b), block = 256.
// ---------------------------------------------------------------------------
__global__ __launch_bounds__(256) void headout_kernel(
    const float* __restrict__ p, const float* __restrict__ fw, const float* __restrict__ fb,
    const float* __restrict__ ap, const float* __restrict__ bp,
    const float* __restrict__ gam, const float* __restrict__ bet,
    const float* __restrict__ rm, const float* __restrict__ rv,
    const float* __restrict__ msw, const float* __restrict__ msb,
    const float* __restrict__ dw, const float* __restrict__ db,
    const float* __restrict__ ws, float* __restrict__ out) {
  int bb = blockIdx.x;
  int t = threadIdx.x;
  __shared__ float red[256 * 17 + 16 * 17];
  __shared__ float yv[64];
  const float* den = ws + DEN_OFF;

  for (int l = 0; l < 4; ++l) {
    float sden_a = 1e-15f, sden_b = 1e-15f;
#pragma unroll
    for (int qq = 0; qq < 4; ++qq) {
      sden_a += den[(((size_t)qq * 2 + 0) * 64 + bb) * 4 + l];
      sden_b += den[(((size_t)qq * 2 + 1) * 64 + bb) * 4 + l];
    }
    float inv_a = 1.0f / sden_a;
    float inv_b = 1.0f / sden_b;

    float4 A = make_float4(0.f, 0.f, 0.f, 0.f), B = make_float4(0.f, 0.f, 0.f, 0.f);
#pragma unroll
    for (int qq = 0; qq < 4; ++qq) {
      const float4* pa_ = reinterpret_cast<const float4*>(
          ws + PA_OFF + ((((size_t)qq * 2 + 0) * 64 + bb) * 4 + l) * HH_);
      const float4* pb_ = reinterpret_cast<const float4*>(
          ws + PA_OFF + ((((size_t)qq * 2 + 1) * 64 + bb) * 4 + l) * HH_);
      float4 va = pa_[t], vb = pb_[t];
      A.x += va.x; A.y += va.y; A.z += va.z; A.w += va.w;
      B.x += vb.x; B.y += vb.y; B.z += vb.z; B.w += vb.w;
    }

    float4 pv = reinterpret_cast<const float4*>(p + ((size_t)bb * LL_ + l) * HH_)[t];
    float av[4] = {A.x * inv_a, A.y * inv_a, A.z * inv_a, A.w * inv_a};
    float bv[4] = {B.x * inv_b, B.y * inv_b, B.z * inv_b, B.w * inv_b};
    float cp[4] = {pv.x, pv.y, pv.z, pv.w};

    float part[16];
#pragma unroll
    for (int o = 0; o < 16; ++o) part[o] = 0.f;

    const float* wl = fw + (size_t)l * 5120 * 16;
#pragma unroll
    for (int j = 0; j < 4; ++j) {
      int h = t * 4 + j;
      float c[5] = {cp[j], av[j], bv[j], cp[j] * av[j], cp[j] * bv[j]};
#pragma unroll
      for (int sec = 0; sec < 5; ++sec) {
        const float4* wr = reinterpret_cast<const float4*>(wl + ((size_t)sec * 1024 + h) * 16);
#pragma unroll
        for (int o4 = 0; o4 < 4; ++o4) {
          float4 w4 = wr[o4];
          part[o4 * 4 + 0] += c[sec] * w4.x;
          part[o4 * 4 + 1] += c[sec] * w4.y;
          part[o4 * 4 + 2] += c[sec] * w4.z;
          part[o4 * 4 + 3] += c[sec] * w4.w;
        }
      }
    }

#pragma unroll
    for (int o = 0; o < 16; ++o) red[t * 17 + o] = part[o];
    __syncthreads();
    {
      int o = t & 15, g = t >> 4;
      float sacc = 0.f;
#pragma unroll
      for (int i = 0; i < 16; ++i) sacc += red[(g * 16 + i) * 17 + o];
      red[256 * 17 + g * 17 + o] = sacc;
    }
    __syncthreads();
    if (t < 16) {
      float sacc = 0.f;
#pragma unroll
      for (int g = 0; g < 16; ++g) sacc += red[256 * 17 + g * 17 + t];
      yv[l * 16 + t] = sacc + fb[l * 16 + t];
    }
    __syncthreads();
  }

  if (t < 64) {
    int k = t;
    float y = yv[k];
    y = (y - rm[k]) * rsqrtf(rv[k] + 1e-5f) * gam[k] + bet[k];
    y = fmaxf(y, 0.f);
    float w0 = dw[0], b0 = db[0];
    float ape = tanhf(ap[bb] * w0 + b0);
    float bpe = tanhf(bp[bb] * w0 + b0);
#pragma unroll
    for (int c = 0; c < 3; ++c) {
      float v = y * msw[k * 3 + c];
#pragma unroll
      for (int off = 32; off > 0; off >>= 1) v += __shfl_xor(v, off);
      if (k == 0) out[bb * 3 + c] = v + ape * msw[64 * 3 + c] + bpe * msw[65 * 3 + c] + msb[c];
    }
  }
}

extern "C" void kernel_launch(void* const* d_in, const int* in_sizes, int n_in,
                              void* d_out, int out_size, void* d_ws, size_t ws_size,
                              hipStream_t stream) {
  (void)in_sizes; (void)n_in; (void)out_size; (void)ws_size;
  const float* a = (const float*)d_in[0];
  const float* b = (const float*)d_in[1];
  const float* p = (const float*)d_in[2];
  const float* ap = (const float*)d_in[3];
  const float* bp = (const float*)d_in[4];
  const float* ffnn_w = (const float*)d_in[5];
  const float* ffnn_b = (const float*)d_in[6];
  const float* bn_g = (const float*)d_in[7];
  const float* bn_b = (const float*)d_in[8];
  const float* bn_rm = (const float*)d_in[9];
  const float* bn_rv = (const float*)d_in[10];
  const float* ms_w = (const float*)d_in[11];
  const float* ms_b = (const float*)d_in[12];
  const float* dist_w = (const float*)d_in[13];
  const float* dist_b = (const float*)d_in[14];
  float* ws = (float*)d_ws;
  float* out = (float*)d_out;

  hipLaunchKernelGGL((attn_pool<0>), dim3(512), dim3(512), 0, stream, a, b, p, ws);
  hipLaunchKernelGGL((attn_pool<1>), dim3(512), dim3(512), 0, stream, a, b, p, ws);
  hipLaunchKernelGGL(headout_kernel, dim3(64), dim3(256), 0, stream,
                     p, ffnn_w, ffnn_b, ap, bp, bn_g, bn_b, bn_rm, bn_rv,
                     ms_w, ms_b, dist_w, dist_b, ws, out);
}